// Round 8
// baseline (480.874 us; speedup 1.0000x reference)
//
#include <hip/hip_runtime.h>

#define NC 4
#define CS 512
#define NS 256
#define HD 512
#define H  256
#define GAMMA_F 12.0f
#define PHASE_SCALE 62.83185307179586477f   // pi / 0.05

#define KT 32        // k-steps per staging round
#define ROUNDS 2     // 64 / KT
#define KSPLIT 4     // k-slices (64 k each)
#define PAD 2        // float2 pad: row stride 34 f2 -> b128 reads conflict-free

// Round 8: LDS-latency attack. Keep 512-block/KSPLIT=4 shape (known-good L2
// behavior). KT=32 halves barriers; ds_read_b128 (2 kk per instr, stride-34
// padding); explicit one-step LDS->reg prefetch pipeline in the kk loop;
// round-7 global prefetch kept.
// grid: 4 chunks * 4 kslices * 8 hTiles(64) * 4 tTiles(64) = 512 blocks
__global__ __launch_bounds__(256, 2) void score_partial(
    const float* __restrict__ heads,     // 2048 x 512
    const float* __restrict__ relations, // 2048 x 256
    const float* __restrict__ tails,     // 1024 x 512
    float* __restrict__ part)            // 4 planes of [4][512][256]
{
    __shared__ __align__(16) float2 sh[64][KT + PAD];
    __shared__ __align__(16) float2 st[64][KT + PAD];

    int bid = blockIdx.x;
    int c    = bid >> 7;          // chunk
    int rem  = bid & 127;
    int ks   = rem >> 5;          // k-slice 0..3
    int rem2 = rem & 31;
    int hT   = rem2 >> 2;         // 0..7
    int tT   = rem2 & 3;          // 0..3

    int hBase = c * CS + hT * 64;     // global head row
    int tBase = c * NS + tT * 64;     // global tail row
    int kSlice = ks * 64;             // k range [kSlice, kSlice+64)

    int tid = threadIdx.x;
    int tx = tid & 15;            // tail micro index
    int ty = tid >> 4;            // head micro index

    // staging: each thread covers rows rowA and rowA+32, 4 k's at k4
    int rowA = tid >> 3;          // 0..31
    int rowB = rowA + 32;
    int k4   = (tid & 7) * 4;     // 0,4,...,28

    const float* hA = heads + (size_t)(hBase + rowA) * HD + kSlice + k4;
    const float* hB = heads + (size_t)(hBase + rowB) * HD + kSlice + k4;
    const float* rA = relations + (size_t)(hBase + rowA) * H + kSlice + k4;
    const float* rB = relations + (size_t)(hBase + rowB) * H + kSlice + k4;
    const float* tA = tails + (size_t)(tBase + rowA) * HD + kSlice + k4;
    const float* tB = tails + (size_t)(tBase + rowB) * HD + kSlice + k4;

    float acc[4][4];
    #pragma unroll
    for (int m = 0; m < 4; ++m)
        #pragma unroll
        for (int n = 0; n < 4; ++n) acc[m][n] = 0.f;

    // ---- prologue: global loads for round 0 ----
    float4 hreA = *reinterpret_cast<const float4*>(hA);
    float4 himA = *reinterpret_cast<const float4*>(hA + H);
    float4 relA = *reinterpret_cast<const float4*>(rA);
    float4 treA = *reinterpret_cast<const float4*>(tA);
    float4 timA = *reinterpret_cast<const float4*>(tA + H);
    float4 hreB = *reinterpret_cast<const float4*>(hB);
    float4 himB = *reinterpret_cast<const float4*>(hB + H);
    float4 relB = *reinterpret_cast<const float4*>(rB);
    float4 treB = *reinterpret_cast<const float4*>(tB);
    float4 timB = *reinterpret_cast<const float4*>(tB + H);

    #pragma unroll
    for (int r = 0; r < ROUNDS; ++r) {
        __syncthreads();   // previous round's LDS reads complete

        // ---- rotate + stage current round's registers ----
        {
            float s, cc;
            __sincosf(relA.x * PHASE_SCALE, &s, &cc);
            sh[rowA][k4 + 0] = make_float2(hreA.x * cc - himA.x * s,
                                           hreA.x * s + himA.x * cc);
            __sincosf(relA.y * PHASE_SCALE, &s, &cc);
            sh[rowA][k4 + 1] = make_float2(hreA.y * cc - himA.y * s,
                                           hreA.y * s + himA.y * cc);
            __sincosf(relA.z * PHASE_SCALE, &s, &cc);
            sh[rowA][k4 + 2] = make_float2(hreA.z * cc - himA.z * s,
                                           hreA.z * s + himA.z * cc);
            __sincosf(relA.w * PHASE_SCALE, &s, &cc);
            sh[rowA][k4 + 3] = make_float2(hreA.w * cc - himA.w * s,
                                           hreA.w * s + himA.w * cc);
            __sincosf(relB.x * PHASE_SCALE, &s, &cc);
            sh[rowB][k4 + 0] = make_float2(hreB.x * cc - himB.x * s,
                                           hreB.x * s + himB.x * cc);
            __sincosf(relB.y * PHASE_SCALE, &s, &cc);
            sh[rowB][k4 + 1] = make_float2(hreB.y * cc - himB.y * s,
                                           hreB.y * s + himB.y * cc);
            __sincosf(relB.z * PHASE_SCALE, &s, &cc);
            sh[rowB][k4 + 2] = make_float2(hreB.z * cc - himB.z * s,
                                           hreB.z * s + himB.z * cc);
            __sincosf(relB.w * PHASE_SCALE, &s, &cc);
            sh[rowB][k4 + 3] = make_float2(hreB.w * cc - himB.w * s,
                                           hreB.w * s + himB.w * cc);
        }
        st[rowA][k4 + 0] = make_float2(treA.x, timA.x);
        st[rowA][k4 + 1] = make_float2(treA.y, timA.y);
        st[rowA][k4 + 2] = make_float2(treA.z, timA.z);
        st[rowA][k4 + 3] = make_float2(treA.w, timA.w);
        st[rowB][k4 + 0] = make_float2(treB.x, timB.x);
        st[rowB][k4 + 1] = make_float2(treB.y, timB.y);
        st[rowB][k4 + 2] = make_float2(treB.z, timB.z);
        st[rowB][k4 + 3] = make_float2(treB.w, timB.w);

        __syncthreads();   // staging visible

        // ---- prefetch NEXT round's globals; latency overlaps compute ----
        if (r + 1 < ROUNDS) {
            int o = (r + 1) * KT;
            hreA = *reinterpret_cast<const float4*>(hA + o);
            himA = *reinterpret_cast<const float4*>(hA + o + H);
            relA = *reinterpret_cast<const float4*>(rA + o);
            treA = *reinterpret_cast<const float4*>(tA + o);
            timA = *reinterpret_cast<const float4*>(tA + o + H);
            hreB = *reinterpret_cast<const float4*>(hB + o);
            himB = *reinterpret_cast<const float4*>(hB + o + H);
            relB = *reinterpret_cast<const float4*>(rB + o);
            treB = *reinterpret_cast<const float4*>(tB + o);
            timB = *reinterpret_cast<const float4*>(tB + o + H);
        }

        // ---- inner loop: b128 reads (2 kk at once), 1-step reg prefetch ----
        float4 ch[4], ct[4], nh[4], nt[4];
        #pragma unroll
        for (int i = 0; i < 4; ++i) {
            ch[i] = *reinterpret_cast<const float4*>(&sh[ty + 16 * i][0]);
            ct[i] = *reinterpret_cast<const float4*>(&st[tx + 16 * i][0]);
        }
        #pragma unroll
        for (int kk = 0; kk < KT; kk += 2) {
            if (kk + 2 < KT) {
                #pragma unroll
                for (int i = 0; i < 4; ++i) {
                    nh[i] = *reinterpret_cast<const float4*>(&sh[ty + 16 * i][kk + 2]);
                    nt[i] = *reinterpret_cast<const float4*>(&st[tx + 16 * i][kk + 2]);
                }
            }
            #pragma unroll
            for (int m = 0; m < 4; ++m) {
                #pragma unroll
                for (int n = 0; n < 4; ++n) {
                    float dr0 = ch[m].x - ct[n].x;
                    float di0 = ch[m].y - ct[n].y;
                    float dr1 = ch[m].z - ct[n].z;
                    float di1 = ch[m].w - ct[n].w;
                    acc[m][n] += __builtin_amdgcn_sqrtf(dr0 * dr0 + di0 * di0);
                    acc[m][n] += __builtin_amdgcn_sqrtf(dr1 * dr1 + di1 * di1);
                }
            }
            if (kk + 2 < KT) {
                #pragma unroll
                for (int i = 0; i < 4; ++i) { ch[i] = nh[i]; ct[i] = nt[i]; }
            }
        }
    }

    // epilogue: plain stores of this k-slice's partial plane
    float* plane = part + (size_t)ks * (NC * CS * NS);
    size_t cbase = (size_t)c * CS * NS;
    #pragma unroll
    for (int m = 0; m < 4; ++m) {
        int i0 = hT * 64 + ty + 16 * m;
        #pragma unroll
        for (int n = 0; n < 4; ++n) {
            int j0 = tT * 64 + tx + 16 * n;
            plane[cbase + (size_t)i0 * NS + j0] = acc[m][n];
        }
    }
}

// out = GAMMA - sum of 4 planes; 131072 threads, one float4 each
__global__ __launch_bounds__(256) void reduce_kernel(
    const float* __restrict__ part, float* __restrict__ out)
{
    const int PLANE = NC * CS * NS;   // 524288
    int idx = (blockIdx.x * 256 + threadIdx.x) * 4;
    float sx = 0.f, sy = 0.f, sz = 0.f, sw = 0.f;
    #pragma unroll
    for (int p = 0; p < KSPLIT; ++p) {
        float4 v = *reinterpret_cast<const float4*>(part + (size_t)p * PLANE + idx);
        sx += v.x; sy += v.y; sz += v.z; sw += v.w;
    }
    float4 r;
    r.x = GAMMA_F - sx;
    r.y = GAMMA_F - sy;
    r.z = GAMMA_F - sz;
    r.w = GAMMA_F - sw;
    *reinterpret_cast<float4*>(out + idx) = r;
}

extern "C" void kernel_launch(void* const* d_in, const int* in_sizes, int n_in,
                              void* d_out, int out_size, void* d_ws, size_t ws_size,
                              hipStream_t stream) {
    (void)in_sizes; (void)n_in; (void)ws_size; (void)out_size;
    const float* heads = (const float*)d_in[0];
    const float* rels  = (const float*)d_in[1];
    const float* tails = (const float*)d_in[2];
    float* part = (float*)d_ws;   // 4 planes x 2 MB = 8 MB

    score_partial<<<512, 256, 0, stream>>>(heads, rels, tails, part);
    reduce_kernel<<<512, 256, 0, stream>>>(part, (float*)d_out);
}

// Round 9
// 120.644 us; speedup vs baseline: 3.9859x; 3.9859x over previous
//
#include <hip/hip_runtime.h>

#define NC 4
#define CS 512
#define NS 256
#define HD 512
#define H  256
#define GAMMA_F 12.0f
#define PHASE_SCALE 62.83185307179586477f   // pi / 0.05

#define KT 32        // k-steps per staging round
#define ROUNDS 2     // 64 / KT
#define KSPLIT 4     // k-slices (64 k each)
#define STRIDE 34    // float2 per LDS row: even (f4-aligned rows), quad=(row+kf4)%8

// Round 9: b128 LDS path with engineered bank layout; NO register pipelines
// (round 8's spill: 128 VGPR + 1.2GB scratch traffic). Simple round-5 loop
// structure. Staging: srow=tid&63, sa=(tid>>6)*8, float4 writes -> wave
// lanes rotate across quads (conflict-free). Inner: float4 reads, 2 kk/instr.
// grid: 4 chunks * 4 kslices * 8 hTiles(64) * 4 tTiles(64) = 512 blocks
__global__ __launch_bounds__(256, 2) void score_partial(
    const float* __restrict__ heads,     // 2048 x 512
    const float* __restrict__ relations, // 2048 x 256
    const float* __restrict__ tails,     // 1024 x 512
    float* __restrict__ part)            // 4 planes of [4][512][256]
{
    __shared__ __align__(16) float2 sh[64 * STRIDE];
    __shared__ __align__(16) float2 st[64 * STRIDE];

    int bid = blockIdx.x;
    int c    = bid >> 7;          // chunk
    int rem  = bid & 127;
    int ks   = rem >> 5;          // k-slice 0..3
    int rem2 = rem & 31;
    int hT   = rem2 >> 2;         // 0..7
    int tT   = rem2 & 3;          // 0..3

    int hBase = c * CS + hT * 64;     // global head row
    int tBase = c * NS + tT * 64;     // global tail row
    int kSlice = ks * 64;             // k range [kSlice, kSlice+64)

    int tid = threadIdx.x;
    int tx = tid & 15;            // tail micro index
    int ty = tid >> 4;            // head micro index

    // staging: one row per thread, 8 consecutive k's; sa uniform per wave
    int srow = tid & 63;          // 0..63
    int sa   = (tid >> 6) * 8;    // 0,8,16,24

    const float* hrow = heads + (size_t)(hBase + srow) * HD + kSlice + sa;
    const float* rrow = relations + (size_t)(hBase + srow) * H + kSlice + sa;
    const float* trow = tails + (size_t)(tBase + srow) * HD + kSlice + sa;

    float acc[4][4];
    #pragma unroll
    for (int m = 0; m < 4; ++m)
        #pragma unroll
        for (int n = 0; n < 4; ++n) acc[m][n] = 0.f;

    for (int r = 0; r < ROUNDS; ++r) {
        int o = r * KT;
        // ---- global loads (8 k's per array) ----
        float4 hre0 = *reinterpret_cast<const float4*>(hrow + o);
        float4 hre1 = *reinterpret_cast<const float4*>(hrow + o + 4);
        float4 him0 = *reinterpret_cast<const float4*>(hrow + o + H);
        float4 him1 = *reinterpret_cast<const float4*>(hrow + o + H + 4);
        float4 rel0 = *reinterpret_cast<const float4*>(rrow + o);
        float4 rel1 = *reinterpret_cast<const float4*>(rrow + o + 4);
        float4 tre0 = *reinterpret_cast<const float4*>(trow + o);
        float4 tre1 = *reinterpret_cast<const float4*>(trow + o + 4);
        float4 tim0 = *reinterpret_cast<const float4*>(trow + o + H);
        float4 tim1 = *reinterpret_cast<const float4*>(trow + o + H + 4);

        __syncthreads();   // previous round's LDS reads complete

        // ---- rotate + stage, float4 writes (conflict-free quad rotation) ----
        float4* shp = reinterpret_cast<float4*>(&sh[srow * STRIDE + sa]);
        float4* stp = reinterpret_cast<float4*>(&st[srow * STRIDE + sa]);
        {
            float s, cc; float4 w;
            __sincosf(rel0.x * PHASE_SCALE, &s, &cc);
            w.x = hre0.x * cc - him0.x * s;  w.y = hre0.x * s + him0.x * cc;
            __sincosf(rel0.y * PHASE_SCALE, &s, &cc);
            w.z = hre0.y * cc - him0.y * s;  w.w = hre0.y * s + him0.y * cc;
            shp[0] = w;
            __sincosf(rel0.z * PHASE_SCALE, &s, &cc);
            w.x = hre0.z * cc - him0.z * s;  w.y = hre0.z * s + him0.z * cc;
            __sincosf(rel0.w * PHASE_SCALE, &s, &cc);
            w.z = hre0.w * cc - him0.w * s;  w.w = hre0.w * s + him0.w * cc;
            shp[1] = w;
            __sincosf(rel1.x * PHASE_SCALE, &s, &cc);
            w.x = hre1.x * cc - him1.x * s;  w.y = hre1.x * s + him1.x * cc;
            __sincosf(rel1.y * PHASE_SCALE, &s, &cc);
            w.z = hre1.y * cc - him1.y * s;  w.w = hre1.y * s + him1.y * cc;
            shp[2] = w;
            __sincosf(rel1.z * PHASE_SCALE, &s, &cc);
            w.x = hre1.z * cc - him1.z * s;  w.y = hre1.z * s + him1.z * cc;
            __sincosf(rel1.w * PHASE_SCALE, &s, &cc);
            w.z = hre1.w * cc - him1.w * s;  w.w = hre1.w * s + him1.w * cc;
            shp[3] = w;
        }
        stp[0] = make_float4(tre0.x, tim0.x, tre0.y, tim0.y);
        stp[1] = make_float4(tre0.z, tim0.z, tre0.w, tim0.w);
        stp[2] = make_float4(tre1.x, tim1.x, tre1.y, tim1.y);
        stp[3] = make_float4(tre1.z, tim1.z, tre1.w, tim1.w);

        __syncthreads();   // staging visible

        // ---- inner: float4 reads cover 2 kk per instruction ----
        #pragma unroll
        for (int kk = 0; kk < KT; kk += 2) {
            float4 hv[4], tv[4];
            #pragma unroll
            for (int i = 0; i < 4; ++i) {
                hv[i] = *reinterpret_cast<const float4*>(
                    &sh[(ty + 16 * i) * STRIDE + kk]);
                tv[i] = *reinterpret_cast<const float4*>(
                    &st[(tx + 16 * i) * STRIDE + kk]);
            }
            #pragma unroll
            for (int m = 0; m < 4; ++m) {
                #pragma unroll
                for (int n = 0; n < 4; ++n) {
                    float dr0 = hv[m].x - tv[n].x;
                    float di0 = hv[m].y - tv[n].y;
                    float dr1 = hv[m].z - tv[n].z;
                    float di1 = hv[m].w - tv[n].w;
                    float q0 = __builtin_amdgcn_sqrtf(dr0 * dr0 + di0 * di0);
                    float q1 = __builtin_amdgcn_sqrtf(dr1 * dr1 + di1 * di1);
                    acc[m][n] += q0 + q1;
                }
            }
        }
    }

    // epilogue: plain stores of this k-slice's partial plane
    float* plane = part + (size_t)ks * (NC * CS * NS);
    size_t cbase = (size_t)c * CS * NS;
    #pragma unroll
    for (int m = 0; m < 4; ++m) {
        int i0 = hT * 64 + ty + 16 * m;
        #pragma unroll
        for (int n = 0; n < 4; ++n) {
            int j0 = tT * 64 + tx + 16 * n;
            plane[cbase + (size_t)i0 * NS + j0] = acc[m][n];
        }
    }
}

// out = GAMMA - sum of 4 planes; 131072 threads, one float4 each
__global__ __launch_bounds__(256) void reduce_kernel(
    const float* __restrict__ part, float* __restrict__ out)
{
    const int PLANE = NC * CS * NS;   // 524288
    int idx = (blockIdx.x * 256 + threadIdx.x) * 4;
    float sx = 0.f, sy = 0.f, sz = 0.f, sw = 0.f;
    #pragma unroll
    for (int p = 0; p < KSPLIT; ++p) {
        float4 v = *reinterpret_cast<const float4*>(part + (size_t)p * PLANE + idx);
        sx += v.x; sy += v.y; sz += v.z; sw += v.w;
    }
    float4 r;
    r.x = GAMMA_F - sx;
    r.y = GAMMA_F - sy;
    r.z = GAMMA_F - sz;
    r.w = GAMMA_F - sw;
    *reinterpret_cast<float4*>(out + idx) = r;
}

extern "C" void kernel_launch(void* const* d_in, const int* in_sizes, int n_in,
                              void* d_out, int out_size, void* d_ws, size_t ws_size,
                              hipStream_t stream) {
    (void)in_sizes; (void)n_in; (void)ws_size; (void)out_size;
    const float* heads = (const float*)d_in[0];
    const float* rels  = (const float*)d_in[1];
    const float* tails = (const float*)d_in[2];
    float* part = (float*)d_ws;   // 4 planes x 2 MB = 8 MB

    score_partial<<<512, 256, 0, stream>>>(heads, rels, tails, part);
    reduce_kernel<<<512, 256, 0, stream>>>(part, (float*)d_out);
}